// Round 1
// baseline (1296.277 us; speedup 1.0000x reference)
//
#include <hip/hip_runtime.h>

#define N_NODES 100000
#define N_EDGES 3200000
#define F_IN    32
#define H       64
#define L_LAYERS 4
#define A_SZ    6158
#define G_SZ    64

// ---------------------------------------------------------------------------
// CSR build: deg -> prefix scan -> slot fill (counting sort by dst)
// ---------------------------------------------------------------------------

__global__ void count_deg_kernel(const int* __restrict__ ei, int* __restrict__ deg) {
    int e = blockIdx.x * blockDim.x + threadIdx.x;
    if (e < N_EDGES) {
        int dst = ei[N_EDGES + e];
        atomicAdd(&deg[dst], 1);
    }
}

__global__ void scan1_kernel(const int* __restrict__ deg, int* __restrict__ bsum) {
    __shared__ int s[256];
    int t = threadIdx.x;
    int i = blockIdx.x * 256 + t;
    s[t] = (i < N_NODES) ? deg[i] : 0;
    __syncthreads();
    for (int off = 128; off > 0; off >>= 1) {
        if (t < off) s[t] += s[t + off];
        __syncthreads();
    }
    if (t == 0) bsum[blockIdx.x] = s[0];
}

__global__ void scan2_kernel(const int* __restrict__ bsum, int* __restrict__ boff, int nb) {
    __shared__ int s[512];
    int t = threadIdx.x;
    int v = (t < nb) ? bsum[t] : 0;
    s[t] = v;
    __syncthreads();
    for (int off = 1; off < 512; off <<= 1) {
        int x = (t >= off) ? s[t - off] : 0;
        __syncthreads();
        s[t] += x;
        __syncthreads();
    }
    if (t < nb) boff[t] = s[t] - v;  // exclusive
}

__global__ void scan3_kernel(const int* __restrict__ deg, const int* __restrict__ boff,
                             int* __restrict__ row_start, int* __restrict__ cursor,
                             float* __restrict__ inv_deg) {
    __shared__ int s[256];
    int t = threadIdx.x;
    int i = blockIdx.x * 256 + t;
    int v = (i < N_NODES) ? deg[i] : 0;
    s[t] = v;
    __syncthreads();
    for (int off = 1; off < 256; off <<= 1) {
        int x = (t >= off) ? s[t - off] : 0;
        __syncthreads();
        s[t] += x;
        __syncthreads();
    }
    if (i < N_NODES) {
        int rs = boff[blockIdx.x] + s[t] - v;
        row_start[i] = rs;
        cursor[i]    = rs;
        inv_deg[i]   = 1.0f / (float)max(v, 1);
    }
    if (i == 0) row_start[N_NODES] = N_EDGES;
}

__global__ void fill_csr_kernel(const int* __restrict__ ei, int* __restrict__ cursor,
                                int* __restrict__ src_sorted) {
    int e = blockIdx.x * blockDim.x + threadIdx.x;
    if (e < N_EDGES) {
        int src = ei[e];
        int dst = ei[N_EDGES + e];
        int slot = atomicAdd(&cursor[dst], 1);
        src_sorted[slot] = src;
    }
}

// ---------------------------------------------------------------------------
// Encoder: h = relu(x @ W_enc.T + b_enc)   [N,32] x [64,32]^T -> [N,64]
// ---------------------------------------------------------------------------

__global__ __launch_bounds__(256) void encoder_kernel(const float* __restrict__ x,
                                                      const float* __restrict__ W_enc,
                                                      const float* __restrict__ b_enc,
                                                      float* __restrict__ h) {
    __shared__ float Wt[F_IN][H + 1];  // Wt[k][f] = W_enc[f*32+k]
    __shared__ float xl[4][F_IN];
    int t = threadIdx.x;
    #pragma unroll
    for (int r = 0; r < 8; ++r) {
        int idx = r * 256 + t;
        Wt[idx & 31][idx >> 5] = W_enc[idx];
    }
    int nb = blockIdx.x * 4;
    if (t < 128) ((float*)xl)[t] = x[nb * F_IN + t];
    __syncthreads();
    int n = t >> 6;
    int f = t & 63;
    float acc = b_enc[f];
    #pragma unroll
    for (int k = 0; k < F_IN; ++k) acc += xl[n][k] * Wt[k][f];
    h[(nb + n) * H + f] = fmaxf(acc, 0.0f);
}

// ---------------------------------------------------------------------------
// Aggregate: agg[n] = mean over incoming neighbors of h[src]
// one wave per node, lane = feature
// ---------------------------------------------------------------------------

__global__ __launch_bounds__(256) void aggregate_kernel(const float* __restrict__ h,
                                                        const int* __restrict__ row_start,
                                                        const int* __restrict__ src_sorted,
                                                        const float* __restrict__ inv_deg,
                                                        float* __restrict__ agg) {
    int wid = blockIdx.x * 4 + (threadIdx.x >> 6);
    int f = threadIdx.x & 63;
    if (wid >= N_NODES) return;
    int s = row_start[wid];
    int e = row_start[wid + 1];
    float a0 = 0.f, a1 = 0.f, a2 = 0.f, a3 = 0.f;
    int j = s;
    for (; j + 3 < e; j += 4) {
        int s0 = src_sorted[j], s1 = src_sorted[j + 1];
        int s2 = src_sorted[j + 2], s3 = src_sorted[j + 3];
        a0 += h[s0 * H + f];
        a1 += h[s1 * H + f];
        a2 += h[s2 * H + f];
        a3 += h[s3 * H + f];
    }
    for (; j < e; ++j) a0 += h[src_sorted[j] * H + f];
    agg[wid * H + f] = ((a0 + a1) + (a2 + a3)) * inv_deg[wid];
}

// ---------------------------------------------------------------------------
// SAGE update: h = relu(agg @ Wl.T + bl + h @ Wr.T) + h    (in place)
// 16 nodes per block; weights transposed in LDS (padded, conflict-free)
// ---------------------------------------------------------------------------

__global__ __launch_bounds__(256) void update_kernel(const float* __restrict__ Wl,
                                                     const float* __restrict__ bl,
                                                     const float* __restrict__ Wr,
                                                     const float* __restrict__ agg,
                                                     float* __restrict__ h) {
    __shared__ float Wlt[H][H + 1];   // Wlt[k][f] = Wl[f*64+k]
    __shared__ float Wrt[H][H + 1];
    __shared__ float Al[16][H];
    __shared__ float Hl[16][H];
    int t = threadIdx.x;
    #pragma unroll
    for (int r = 0; r < 16; ++r) {
        int idx = r * 256 + t;
        int f = idx >> 6, k = idx & 63;
        Wlt[k][f] = Wl[idx];
        Wrt[k][f] = Wr[idx];
    }
    int nb = blockIdx.x * 16;
    #pragma unroll
    for (int r = 0; r < 4; ++r) {
        int idx = r * 256 + t;
        ((float*)Al)[idx] = agg[nb * H + idx];
        ((float*)Hl)[idx] = h[nb * H + idx];
    }
    __syncthreads();
    int f = t & 63;
    int q = t >> 6;  // wave id -> node group
    float b = bl[f];
    float acc0 = b, acc1 = b, acc2 = b, acc3 = b;
    #pragma unroll
    for (int k = 0; k < H; ++k) {
        float wl = Wlt[k][f];
        float wr = Wrt[k][f];
        acc0 += Al[q * 4 + 0][k] * wl + Hl[q * 4 + 0][k] * wr;
        acc1 += Al[q * 4 + 1][k] * wl + Hl[q * 4 + 1][k] * wr;
        acc2 += Al[q * 4 + 2][k] * wl + Hl[q * 4 + 2][k] * wr;
        acc3 += Al[q * 4 + 3][k] * wl + Hl[q * 4 + 3][k] * wr;
    }
    h[(nb + q * 4 + 0) * H + f] = fmaxf(acc0, 0.f) + Hl[q * 4 + 0][f];
    h[(nb + q * 4 + 1) * H + f] = fmaxf(acc1, 0.f) + Hl[q * 4 + 1][f];
    h[(nb + q * 4 + 2) * H + f] = fmaxf(acc2, 0.f) + Hl[q * 4 + 2][f];
    h[(nb + q * 4 + 3) * H + f] = fmaxf(acc3, 0.f) + Hl[q * 4 + 3][f];
}

// ---------------------------------------------------------------------------
// Pool: segmented mean over sorted batch ids (run-length + rare atomics)
// ---------------------------------------------------------------------------

__global__ __launch_bounds__(256) void pool_kernel(const float* __restrict__ h,
                                                   const int* __restrict__ batch,
                                                   float* __restrict__ gsum,
                                                   float* __restrict__ gcount) {
    int w = blockIdx.x * 4 + (threadIdx.x >> 6);
    int f = threadIdx.x & 63;
    int n0 = w * 256;
    if (n0 >= N_NODES) return;
    int n1 = min(n0 + 256, N_NODES);
    int curg = batch[n0];
    float acc = 0.f;
    int cnt = 0;
    for (int n = n0; n < n1; ++n) {
        int g = batch[n];
        if (g != curg) {
            atomicAdd(&gsum[curg * H + f], acc);
            if (f == 0) atomicAdd(&gcount[curg], (float)cnt);
            acc = 0.f; cnt = 0; curg = g;
        }
        acc += h[n * H + f];
        ++cnt;
    }
    atomicAdd(&gsum[curg * H + f], acc);
    if (f == 0) atomicAdd(&gcount[curg], (float)cnt);
}

// ---------------------------------------------------------------------------
// Heads
// ---------------------------------------------------------------------------

__global__ __launch_bounds__(256) void policy_kernel(const float* __restrict__ gsum,
                                                     const float* __restrict__ gcount,
                                                     const float* __restrict__ Wp,
                                                     const float* __restrict__ bp,
                                                     float* __restrict__ out) {
    __shared__ float gr[H];
    int g = blockIdx.y;
    int t = threadIdx.x;
    if (t < H) {
        float inv = 1.0f / fmaxf(gcount[g], 1.0f);
        gr[t] = gsum[g * H + t] * inv;
    }
    __syncthreads();
    int a = blockIdx.x * 256 + t;
    if (a >= A_SZ) return;
    const float4* wp4 = (const float4*)(Wp + a * H);
    float acc = bp[a];
    #pragma unroll
    for (int c = 0; c < 16; ++c) {
        float4 wv = wp4[c];
        acc += gr[4 * c + 0] * wv.x + gr[4 * c + 1] * wv.y
             + gr[4 * c + 2] * wv.z + gr[4 * c + 3] * wv.w;
    }
    out[g * A_SZ + a] = acc;
}

__global__ void value_kernel(const float* __restrict__ gsum, const float* __restrict__ gcount,
                             const float* __restrict__ Wv, const float* __restrict__ bv,
                             float* __restrict__ out) {
    int g = threadIdx.x;
    if (g >= G_SZ) return;
    float inv = 1.0f / fmaxf(gcount[g], 1.0f);
    float acc = bv[0];
    #pragma unroll
    for (int k = 0; k < H; ++k) acc += gsum[g * H + k] * inv * Wv[k];
    out[G_SZ * A_SZ + g] = tanhf(acc);
}

// ---------------------------------------------------------------------------

extern "C" void kernel_launch(void* const* d_in, const int* in_sizes, int n_in,
                              void* d_out, int out_size, void* d_ws, size_t ws_size,
                              hipStream_t stream) {
    const float* x     = (const float*)d_in[0];
    const int*   ei    = (const int*)d_in[1];
    const int*   batch = (const int*)d_in[2];
    const float* W_enc = (const float*)d_in[3];
    const float* b_enc = (const float*)d_in[4];
    const float* Wl    = (const float*)d_in[5];
    const float* bl    = (const float*)d_in[6];
    const float* Wr    = (const float*)d_in[7];
    const float* Wp    = (const float*)d_in[8];
    const float* bp    = (const float*)d_in[9];
    const float* Wv    = (const float*)d_in[10];
    const float* bv    = (const float*)d_in[11];
    float* out = (float*)d_out;

    char* ws = (char*)d_ws;
    size_t off = 0;
    auto alloc = [&](size_t bytes) {
        char* p = ws + off;
        off = (off + bytes + 255) & ~(size_t)255;
        return p;
    };
    float* h        = (float*)alloc((size_t)N_NODES * H * 4);
    float* agg      = (float*)alloc((size_t)N_NODES * H * 4);
    int* row_start  = (int*)alloc((size_t)(N_NODES + 1) * 4);
    int* cursor     = (int*)alloc((size_t)N_NODES * 4);
    int* deg        = (int*)alloc((size_t)N_NODES * 4);
    float* inv_deg  = (float*)alloc((size_t)N_NODES * 4);
    int* src_sorted = (int*)alloc((size_t)N_EDGES * 4);
    int* bsum       = (int*)alloc(512 * 4);
    int* boff       = (int*)alloc(512 * 4);
    float* gsum     = (float*)alloc((size_t)(G_SZ * H + G_SZ) * 4);
    float* gcount   = gsum + G_SZ * H;

    const int NB = (N_NODES + 255) / 256;  // 391

    hipMemsetAsync(deg, 0, (size_t)N_NODES * 4, stream);
    count_deg_kernel<<<(N_EDGES + 255) / 256, 256, 0, stream>>>(ei, deg);
    scan1_kernel<<<NB, 256, 0, stream>>>(deg, bsum);
    scan2_kernel<<<1, 512, 0, stream>>>(bsum, boff, NB);
    scan3_kernel<<<NB, 256, 0, stream>>>(deg, boff, row_start, cursor, inv_deg);
    fill_csr_kernel<<<(N_EDGES + 255) / 256, 256, 0, stream>>>(ei, cursor, src_sorted);

    encoder_kernel<<<N_NODES / 4, 256, 0, stream>>>(x, W_enc, b_enc, h);

    for (int l = 0; l < L_LAYERS; ++l) {
        aggregate_kernel<<<(N_NODES + 3) / 4, 256, 0, stream>>>(h, row_start, src_sorted,
                                                                inv_deg, agg);
        update_kernel<<<N_NODES / 16, 256, 0, stream>>>(Wl + (size_t)l * H * H, bl + l * H,
                                                        Wr + (size_t)l * H * H, agg, h);
    }

    hipMemsetAsync(gsum, 0, (size_t)(G_SZ * H + G_SZ) * 4, stream);
    pool_kernel<<<(NB + 3) / 4, 256, 0, stream>>>(h, batch, gsum, gcount);
    policy_kernel<<<dim3((A_SZ + 255) / 256, G_SZ), 256, 0, stream>>>(gsum, gcount, Wp, bp, out);
    value_kernel<<<1, 64, 0, stream>>>(gsum, gcount, Wv, bv, out);
}

// Round 2
// 987.146 us; speedup vs baseline: 1.3132x; 1.3132x over previous
//
#include <hip/hip_runtime.h>

#define N_NODES 100000
#define N_EDGES 3200000
#define F_IN    32
#define H       64
#define L_LAYERS 4
#define A_SZ    6158
#define G_SZ    64

#define NBUCK 391           // ceil(N_NODES / 256): bucket = dst >> 8
#define EPB   8192          // edges per block in bucket passes
#define NEBLK 391           // ceil(N_EDGES / EPB)

// ---------------------------------------------------------------------------
// CSR build, bucketed: all random scatter confined to LDS / 32KB windows.
// bucket b covers nodes [b*256, b*256+256); bucket offsets == CSR offsets
// at bucket granularity, so per-node row_start derives from bucket-local
// histograms (no global count_deg pass needed).
// ---------------------------------------------------------------------------

__global__ __launch_bounds__(256) void bucket_hist_kernel(const int* __restrict__ ei,
                                                          int* __restrict__ bhist) {
    __shared__ int hist[NBUCK];
    int t = threadIdx.x;
    for (int i = t; i < NBUCK; i += 256) hist[i] = 0;
    __syncthreads();
    int base = blockIdx.x * EPB;
    #pragma unroll
    for (int i = 0; i < EPB / 256; ++i) {
        int e = base + i * 256 + t;
        if (e < N_EDGES) atomicAdd(&hist[ei[N_EDGES + e] >> 8], 1);
    }
    __syncthreads();
    for (int i = t; i < NBUCK; i += 256)
        if (hist[i]) atomicAdd(&bhist[i], hist[i]);
}

__global__ void bucket_scan_kernel(const int* __restrict__ bhist,
                                   int* __restrict__ bucket_base,
                                   int* __restrict__ bcursor) {
    __shared__ int s[512];
    int t = threadIdx.x;
    int v = (t < NBUCK) ? bhist[t] : 0;
    s[t] = v;
    __syncthreads();
    for (int off = 1; off < 512; off <<= 1) {
        int x = (t >= off) ? s[t - off] : 0;
        __syncthreads();
        s[t] += x;
        __syncthreads();
    }
    if (t < NBUCK) {
        int excl = s[t] - v;
        bucket_base[t] = excl;
        bcursor[t] = excl;
    }
    if (t == 0) bucket_base[NBUCK] = N_EDGES;
}

// scatter packed (local_dst<<17 | src) into bucket-grouped regions
__global__ __launch_bounds__(256) void bucket_scatter_kernel(const int* __restrict__ ei,
                                                             int* __restrict__ bcursor,
                                                             unsigned int* __restrict__ pairs) {
    __shared__ int hist[NBUCK];
    __shared__ int cur[NBUCK];
    int t = threadIdx.x;
    for (int i = t; i < NBUCK; i += 256) hist[i] = 0;
    __syncthreads();
    int base = blockIdx.x * EPB;
    #pragma unroll
    for (int i = 0; i < EPB / 256; ++i) {
        int e = base + i * 256 + t;
        if (e < N_EDGES) atomicAdd(&hist[ei[N_EDGES + e] >> 8], 1);
    }
    __syncthreads();
    for (int i = t; i < NBUCK; i += 256) {
        int c = hist[i];
        cur[i] = c ? atomicAdd(&bcursor[i], c) : 0;
    }
    __syncthreads();
    #pragma unroll
    for (int i = 0; i < EPB / 256; ++i) {
        int e = base + i * 256 + t;
        if (e < N_EDGES) {
            int src = ei[e];
            int dst = ei[N_EDGES + e];
            int b = dst >> 8;
            int idx = atomicAdd(&cur[b], 1);
            pairs[idx] = ((unsigned int)(dst & 255) << 17) | (unsigned int)src;
        }
    }
}

// per-bucket: per-node counts -> row_start/inv_deg, then rank+write src_sorted
__global__ __launch_bounds__(256) void bucket_rank_kernel(const unsigned int* __restrict__ pairs,
                                                          const int* __restrict__ bucket_base,
                                                          int* __restrict__ row_start,
                                                          float* __restrict__ inv_deg,
                                                          int* __restrict__ src_sorted) {
    __shared__ int cnt[256];
    __shared__ int scn[256];
    __shared__ int cur[256];
    int b = blockIdx.x;
    int t = threadIdx.x;
    int nb0 = b << 8;
    int e0 = bucket_base[b];
    int e1 = bucket_base[b + 1];
    cnt[t] = 0;
    __syncthreads();
    for (int e = e0 + t; e < e1; e += 256)
        atomicAdd(&cnt[pairs[e] >> 17], 1);
    __syncthreads();
    int v = cnt[t];
    scn[t] = v;
    __syncthreads();
    for (int off = 1; off < 256; off <<= 1) {
        int x = (t >= off) ? scn[t - off] : 0;
        __syncthreads();
        scn[t] += x;
        __syncthreads();
    }
    int excl = scn[t] - v;
    int n = nb0 + t;
    if (n < N_NODES) {
        row_start[n] = e0 + excl;
        inv_deg[n] = 1.0f / (float)max(v, 1);
    }
    cur[t] = e0 + excl;
    __syncthreads();
    for (int e = e0 + t; e < e1; e += 256) {
        unsigned int p = pairs[e];
        int slot = atomicAdd(&cur[p >> 17], 1);
        src_sorted[slot] = (int)(p & 0x1FFFFu);
    }
    if (b == 0 && t == 0) row_start[N_NODES] = N_EDGES;
}

// ---------------------------------------------------------------------------
// Encoder: h = relu(x @ W_enc.T + b_enc)
// ---------------------------------------------------------------------------

__global__ __launch_bounds__(256) void encoder_kernel(const float* __restrict__ x,
                                                      const float* __restrict__ W_enc,
                                                      const float* __restrict__ b_enc,
                                                      float* __restrict__ h) {
    __shared__ float Wt[F_IN][H + 1];
    __shared__ float xl[4][F_IN];
    int t = threadIdx.x;
    #pragma unroll
    for (int r = 0; r < 8; ++r) {
        int idx = r * 256 + t;
        Wt[idx & 31][idx >> 5] = W_enc[idx];
    }
    int nb = blockIdx.x * 4;
    if (t < 128) ((float*)xl)[t] = x[nb * F_IN + t];
    __syncthreads();
    int n = t >> 6;
    int f = t & 63;
    float acc = b_enc[f];
    #pragma unroll
    for (int k = 0; k < F_IN; ++k) acc += xl[n][k] * Wt[k][f];
    h[(nb + n) * H + f] = fmaxf(acc, 0.0f);
}

// ---------------------------------------------------------------------------
// Aggregate: mean of h over incoming neighbors; one wave per node
// ---------------------------------------------------------------------------

__global__ __launch_bounds__(256) void aggregate_kernel(const float* __restrict__ h,
                                                        const int* __restrict__ row_start,
                                                        const int* __restrict__ src_sorted,
                                                        const float* __restrict__ inv_deg,
                                                        float* __restrict__ agg) {
    int wid = blockIdx.x * 4 + (threadIdx.x >> 6);
    int f = threadIdx.x & 63;
    if (wid >= N_NODES) return;
    int s = row_start[wid];
    int e = row_start[wid + 1];
    float a0 = 0.f, a1 = 0.f, a2 = 0.f, a3 = 0.f;
    int j = s;
    for (; j + 3 < e; j += 4) {
        int s0 = src_sorted[j], s1 = src_sorted[j + 1];
        int s2 = src_sorted[j + 2], s3 = src_sorted[j + 3];
        a0 += h[s0 * H + f];
        a1 += h[s1 * H + f];
        a2 += h[s2 * H + f];
        a3 += h[s3 * H + f];
    }
    for (; j < e; ++j) a0 += h[src_sorted[j] * H + f];
    agg[wid * H + f] = ((a0 + a1) + (a2 + a3)) * inv_deg[wid];
}

// ---------------------------------------------------------------------------
// SAGE update: h = relu(agg @ Wl.T + bl + h @ Wr.T) + h   (in place)
// ---------------------------------------------------------------------------

__global__ __launch_bounds__(256) void update_kernel(const float* __restrict__ Wl,
                                                     const float* __restrict__ bl,
                                                     const float* __restrict__ Wr,
                                                     const float* __restrict__ agg,
                                                     float* __restrict__ h) {
    __shared__ float Wlt[H][H + 1];
    __shared__ float Wrt[H][H + 1];
    __shared__ float Al[16][H];
    __shared__ float Hl[16][H];
    int t = threadIdx.x;
    #pragma unroll
    for (int r = 0; r < 16; ++r) {
        int idx = r * 256 + t;
        int f = idx >> 6, k = idx & 63;
        Wlt[k][f] = Wl[idx];
        Wrt[k][f] = Wr[idx];
    }
    int nb = blockIdx.x * 16;
    #pragma unroll
    for (int r = 0; r < 4; ++r) {
        int idx = r * 256 + t;
        ((float*)Al)[idx] = agg[nb * H + idx];
        ((float*)Hl)[idx] = h[nb * H + idx];
    }
    __syncthreads();
    int f = t & 63;
    int q = t >> 6;
    float b = bl[f];
    float acc0 = b, acc1 = b, acc2 = b, acc3 = b;
    #pragma unroll
    for (int k = 0; k < H; ++k) {
        float wl = Wlt[k][f];
        float wr = Wrt[k][f];
        acc0 += Al[q * 4 + 0][k] * wl + Hl[q * 4 + 0][k] * wr;
        acc1 += Al[q * 4 + 1][k] * wl + Hl[q * 4 + 1][k] * wr;
        acc2 += Al[q * 4 + 2][k] * wl + Hl[q * 4 + 2][k] * wr;
        acc3 += Al[q * 4 + 3][k] * wl + Hl[q * 4 + 3][k] * wr;
    }
    h[(nb + q * 4 + 0) * H + f] = fmaxf(acc0, 0.f) + Hl[q * 4 + 0][f];
    h[(nb + q * 4 + 1) * H + f] = fmaxf(acc1, 0.f) + Hl[q * 4 + 1][f];
    h[(nb + q * 4 + 2) * H + f] = fmaxf(acc2, 0.f) + Hl[q * 4 + 2][f];
    h[(nb + q * 4 + 3) * H + f] = fmaxf(acc3, 0.f) + Hl[q * 4 + 3][f];
}

// ---------------------------------------------------------------------------
// Pool + heads
// ---------------------------------------------------------------------------

__global__ __launch_bounds__(256) void pool_kernel(const float* __restrict__ h,
                                                   const int* __restrict__ batch,
                                                   float* __restrict__ gsum,
                                                   float* __restrict__ gcount) {
    int w = blockIdx.x * 4 + (threadIdx.x >> 6);
    int f = threadIdx.x & 63;
    int n0 = w * 256;
    if (n0 >= N_NODES) return;
    int n1 = min(n0 + 256, N_NODES);
    int curg = batch[n0];
    float acc = 0.f;
    int cnt = 0;
    for (int n = n0; n < n1; ++n) {
        int g = batch[n];
        if (g != curg) {
            atomicAdd(&gsum[curg * H + f], acc);
            if (f == 0) atomicAdd(&gcount[curg], (float)cnt);
            acc = 0.f; cnt = 0; curg = g;
        }
        acc += h[n * H + f];
        ++cnt;
    }
    atomicAdd(&gsum[curg * H + f], acc);
    if (f == 0) atomicAdd(&gcount[curg], (float)cnt);
}

__global__ __launch_bounds__(256) void policy_kernel(const float* __restrict__ gsum,
                                                     const float* __restrict__ gcount,
                                                     const float* __restrict__ Wp,
                                                     const float* __restrict__ bp,
                                                     float* __restrict__ out) {
    __shared__ float gr[H];
    int g = blockIdx.y;
    int t = threadIdx.x;
    if (t < H) {
        float inv = 1.0f / fmaxf(gcount[g], 1.0f);
        gr[t] = gsum[g * H + t] * inv;
    }
    __syncthreads();
    int a = blockIdx.x * 256 + t;
    if (a >= A_SZ) return;
    const float4* wp4 = (const float4*)(Wp + a * H);
    float acc = bp[a];
    #pragma unroll
    for (int c = 0; c < 16; ++c) {
        float4 wv = wp4[c];
        acc += gr[4 * c + 0] * wv.x + gr[4 * c + 1] * wv.y
             + gr[4 * c + 2] * wv.z + gr[4 * c + 3] * wv.w;
    }
    out[g * A_SZ + a] = acc;
}

__global__ void value_kernel(const float* __restrict__ gsum, const float* __restrict__ gcount,
                             const float* __restrict__ Wv, const float* __restrict__ bv,
                             float* __restrict__ out) {
    int g = threadIdx.x;
    if (g >= G_SZ) return;
    float inv = 1.0f / fmaxf(gcount[g], 1.0f);
    float acc = bv[0];
    #pragma unroll
    for (int k = 0; k < H; ++k) acc += gsum[g * H + k] * inv * Wv[k];
    out[G_SZ * A_SZ + g] = tanhf(acc);
}

// ---------------------------------------------------------------------------

extern "C" void kernel_launch(void* const* d_in, const int* in_sizes, int n_in,
                              void* d_out, int out_size, void* d_ws, size_t ws_size,
                              hipStream_t stream) {
    const float* x     = (const float*)d_in[0];
    const int*   ei    = (const int*)d_in[1];
    const int*   batch = (const int*)d_in[2];
    const float* W_enc = (const float*)d_in[3];
    const float* b_enc = (const float*)d_in[4];
    const float* Wl    = (const float*)d_in[5];
    const float* bl    = (const float*)d_in[6];
    const float* Wr    = (const float*)d_in[7];
    const float* Wp    = (const float*)d_in[8];
    const float* bp    = (const float*)d_in[9];
    const float* Wv    = (const float*)d_in[10];
    const float* bv    = (const float*)d_in[11];
    float* out = (float*)d_out;

    char* ws = (char*)d_ws;
    size_t off = 0;
    auto alloc = [&](size_t bytes) {
        char* p = ws + off;
        off = (off + bytes + 255) & ~(size_t)255;
        return p;
    };
    float* h          = (float*)alloc((size_t)N_NODES * H * 4);
    float* agg        = (float*)alloc((size_t)N_NODES * H * 4);
    int* row_start    = (int*)alloc((size_t)(N_NODES + 1) * 4);
    float* inv_deg    = (float*)alloc((size_t)N_NODES * 4);
    int* src_sorted   = (int*)alloc((size_t)N_EDGES * 4);
    unsigned int* pairs = (unsigned int*)alloc((size_t)N_EDGES * 4);
    int* bhist        = (int*)alloc((NBUCK + 8) * 4);
    int* bucket_base  = (int*)alloc((NBUCK + 8) * 4);
    int* bcursor      = (int*)alloc((NBUCK + 8) * 4);
    float* gsum       = (float*)alloc((size_t)(G_SZ * H + G_SZ) * 4);
    float* gcount     = gsum + G_SZ * H;

    const int NB = (N_NODES + 255) / 256;  // 391

    // CSR build (bucketed)
    hipMemsetAsync(bhist, 0, NBUCK * 4, stream);
    bucket_hist_kernel<<<NEBLK, 256, 0, stream>>>(ei, bhist);
    bucket_scan_kernel<<<1, 512, 0, stream>>>(bhist, bucket_base, bcursor);
    bucket_scatter_kernel<<<NEBLK, 256, 0, stream>>>(ei, bcursor, pairs);
    bucket_rank_kernel<<<NBUCK, 256, 0, stream>>>(pairs, bucket_base, row_start,
                                                  inv_deg, src_sorted);

    encoder_kernel<<<N_NODES / 4, 256, 0, stream>>>(x, W_enc, b_enc, h);

    for (int l = 0; l < L_LAYERS; ++l) {
        aggregate_kernel<<<(N_NODES + 3) / 4, 256, 0, stream>>>(h, row_start, src_sorted,
                                                                inv_deg, agg);
        update_kernel<<<N_NODES / 16, 256, 0, stream>>>(Wl + (size_t)l * H * H, bl + l * H,
                                                        Wr + (size_t)l * H * H, agg, h);
    }

    hipMemsetAsync(gsum, 0, (size_t)(G_SZ * H + G_SZ) * 4, stream);
    pool_kernel<<<(NB + 3) / 4, 256, 0, stream>>>(h, batch, gsum, gcount);
    policy_kernel<<<dim3((A_SZ + 255) / 256, G_SZ), 256, 0, stream>>>(gsum, gcount, Wp, bp, out);
    value_kernel<<<1, 64, 0, stream>>>(gsum, gcount, Wv, bv, out);
}

// Round 3
// 772.238 us; speedup vs baseline: 1.6786x; 1.2783x over previous
//
#include <hip/hip_runtime.h>
#include <hip/hip_bf16.h>

#define N_NODES 100000
#define N_EDGES 3200000
#define F_IN    32
#define H       64
#define L_LAYERS 4
#define A_SZ    6158
#define G_SZ    64

#define NBUCK 391           // ceil(N_NODES / 256): bucket = dst >> 8
#define EPB   8192          // edges per block in bucket passes
#define NEBLK 391           // ceil(N_EDGES / EPB)

__device__ __forceinline__ float bflo(unsigned u) { return __uint_as_float(u << 16); }
__device__ __forceinline__ float bfhi(unsigned u) { return __uint_as_float(u & 0xffff0000u); }
__device__ __forceinline__ unsigned short f2bf(float f) {
    union { __hip_bfloat16 b; unsigned short u; } c;
    c.b = __float2bfloat16(f);
    return c.u;
}

// ---------------------------------------------------------------------------
// CSR build, bucketed (unchanged from round 2)
// ---------------------------------------------------------------------------

__global__ __launch_bounds__(256) void bucket_hist_kernel(const int* __restrict__ ei,
                                                          int* __restrict__ bhist) {
    __shared__ int hist[NBUCK];
    int t = threadIdx.x;
    for (int i = t; i < NBUCK; i += 256) hist[i] = 0;
    __syncthreads();
    int base = blockIdx.x * EPB;
    #pragma unroll
    for (int i = 0; i < EPB / 256; ++i) {
        int e = base + i * 256 + t;
        if (e < N_EDGES) atomicAdd(&hist[ei[N_EDGES + e] >> 8], 1);
    }
    __syncthreads();
    for (int i = t; i < NBUCK; i += 256)
        if (hist[i]) atomicAdd(&bhist[i], hist[i]);
}

__global__ void bucket_scan_kernel(const int* __restrict__ bhist,
                                   int* __restrict__ bucket_base,
                                   int* __restrict__ bcursor) {
    __shared__ int s[512];
    int t = threadIdx.x;
    int v = (t < NBUCK) ? bhist[t] : 0;
    s[t] = v;
    __syncthreads();
    for (int off = 1; off < 512; off <<= 1) {
        int x = (t >= off) ? s[t - off] : 0;
        __syncthreads();
        s[t] += x;
        __syncthreads();
    }
    if (t < NBUCK) {
        int excl = s[t] - v;
        bucket_base[t] = excl;
        bcursor[t] = excl;
    }
    if (t == 0) bucket_base[NBUCK] = N_EDGES;
}

__global__ __launch_bounds__(256) void bucket_scatter_kernel(const int* __restrict__ ei,
                                                             int* __restrict__ bcursor,
                                                             unsigned int* __restrict__ pairs) {
    __shared__ int hist[NBUCK];
    __shared__ int cur[NBUCK];
    int t = threadIdx.x;
    for (int i = t; i < NBUCK; i += 256) hist[i] = 0;
    __syncthreads();
    int base = blockIdx.x * EPB;
    #pragma unroll
    for (int i = 0; i < EPB / 256; ++i) {
        int e = base + i * 256 + t;
        if (e < N_EDGES) atomicAdd(&hist[ei[N_EDGES + e] >> 8], 1);
    }
    __syncthreads();
    for (int i = t; i < NBUCK; i += 256) {
        int c = hist[i];
        cur[i] = c ? atomicAdd(&bcursor[i], c) : 0;
    }
    __syncthreads();
    #pragma unroll
    for (int i = 0; i < EPB / 256; ++i) {
        int e = base + i * 256 + t;
        if (e < N_EDGES) {
            int src = ei[e];
            int dst = ei[N_EDGES + e];
            int b = dst >> 8;
            int idx = atomicAdd(&cur[b], 1);
            pairs[idx] = ((unsigned int)(dst & 255) << 17) | (unsigned int)src;
        }
    }
}

__global__ __launch_bounds__(256) void bucket_rank_kernel(const unsigned int* __restrict__ pairs,
                                                          const int* __restrict__ bucket_base,
                                                          int* __restrict__ row_start,
                                                          float* __restrict__ inv_deg,
                                                          int* __restrict__ src_sorted) {
    __shared__ int cnt[256];
    __shared__ int scn[256];
    __shared__ int cur[256];
    int b = blockIdx.x;
    int t = threadIdx.x;
    int nb0 = b << 8;
    int e0 = bucket_base[b];
    int e1 = bucket_base[b + 1];
    cnt[t] = 0;
    __syncthreads();
    for (int e = e0 + t; e < e1; e += 256)
        atomicAdd(&cnt[pairs[e] >> 17], 1);
    __syncthreads();
    int v = cnt[t];
    scn[t] = v;
    __syncthreads();
    for (int off = 1; off < 256; off <<= 1) {
        int x = (t >= off) ? scn[t - off] : 0;
        __syncthreads();
        scn[t] += x;
        __syncthreads();
    }
    int excl = scn[t] - v;
    int n = nb0 + t;
    if (n < N_NODES) {
        row_start[n] = e0 + excl;
        inv_deg[n] = 1.0f / (float)max(v, 1);
    }
    cur[t] = e0 + excl;
    __syncthreads();
    for (int e = e0 + t; e < e1; e += 256) {
        unsigned int p = pairs[e];
        int slot = atomicAdd(&cur[p >> 17], 1);
        src_sorted[slot] = (int)(p & 0x1FFFFu);
    }
    if (b == 0 && t == 0) row_start[N_NODES] = N_EDGES;
}

// ---------------------------------------------------------------------------
// Encoder: h = relu(x @ W_enc.T + b_enc); writes fp32 h and bf16 mirror h16
// ---------------------------------------------------------------------------

__global__ __launch_bounds__(256) void encoder_kernel(const float* __restrict__ x,
                                                      const float* __restrict__ W_enc,
                                                      const float* __restrict__ b_enc,
                                                      float* __restrict__ h,
                                                      unsigned short* __restrict__ h16) {
    __shared__ float Wt[F_IN][H + 1];
    __shared__ float xl[4][F_IN];
    int t = threadIdx.x;
    #pragma unroll
    for (int r = 0; r < 8; ++r) {
        int idx = r * 256 + t;
        Wt[idx & 31][idx >> 5] = W_enc[idx];
    }
    int nb = blockIdx.x * 4;
    if (t < 128) ((float*)xl)[t] = x[nb * F_IN + t];
    __syncthreads();
    int n = t >> 6;
    int f = t & 63;
    float acc = b_enc[f];
    #pragma unroll
    for (int k = 0; k < F_IN; ++k) acc += xl[n][k] * Wt[k][f];
    float v = fmaxf(acc, 0.0f);
    h[(nb + n) * H + f] = v;
    h16[(nb + n) * H + f] = f2bf(v);
}

// ---------------------------------------------------------------------------
// Aggregate: mean of h16 rows over incoming neighbors.
// 2 nodes per wave: lanes 0-31 node a, lanes 32-63 node b; lane j holds
// features (2j, 2j+1) packed bf16x2 -> one 128 B coalesced load per edge row.
// ---------------------------------------------------------------------------

__global__ __launch_bounds__(256) void aggregate_kernel(const unsigned short* __restrict__ h16,
                                                        const int* __restrict__ row_start,
                                                        const int* __restrict__ src_sorted,
                                                        const float* __restrict__ inv_deg,
                                                        float* __restrict__ agg) {
    int t = threadIdx.x;
    int wave = (blockIdx.x << 2) + (t >> 6);
    int lane = t & 63;
    int half = lane >> 5;
    int j = lane & 31;
    int node = (wave << 1) + half;
    if (node >= N_NODES) return;
    int s = row_start[node];
    int e = row_start[node + 1];
    float a0 = 0.f, a1 = 0.f, b0 = 0.f, b1 = 0.f;
    float c0 = 0.f, c1 = 0.f, d0 = 0.f, d1 = 0.f;
    int i = s;
    for (; i + 3 < e; i += 4) {
        int s0 = src_sorted[i], s1 = src_sorted[i + 1];
        int s2 = src_sorted[i + 2], s3 = src_sorted[i + 3];
        unsigned u0 = *(const unsigned*)(h16 + (size_t)s0 * H + 2 * j);
        unsigned u1 = *(const unsigned*)(h16 + (size_t)s1 * H + 2 * j);
        unsigned u2 = *(const unsigned*)(h16 + (size_t)s2 * H + 2 * j);
        unsigned u3 = *(const unsigned*)(h16 + (size_t)s3 * H + 2 * j);
        a0 += bflo(u0); a1 += bfhi(u0);
        b0 += bflo(u1); b1 += bfhi(u1);
        c0 += bflo(u2); c1 += bfhi(u2);
        d0 += bflo(u3); d1 += bfhi(u3);
    }
    for (; i < e; ++i) {
        unsigned u = *(const unsigned*)(h16 + (size_t)src_sorted[i] * H + 2 * j);
        a0 += bflo(u); a1 += bfhi(u);
    }
    float inv = inv_deg[node];
    float r0 = ((a0 + b0) + (c0 + d0)) * inv;
    float r1 = ((a1 + b1) + (c1 + d1)) * inv;
    *(float2*)(agg + (size_t)node * H + 2 * j) = make_float2(r0, r1);
}

// ---------------------------------------------------------------------------
// SAGE update: h = relu(agg @ Wl.T + bl + h @ Wr.T) + h; also refresh h16
// ---------------------------------------------------------------------------

__global__ __launch_bounds__(256) void update_kernel(const float* __restrict__ Wl,
                                                     const float* __restrict__ bl,
                                                     const float* __restrict__ Wr,
                                                     const float* __restrict__ agg,
                                                     float* __restrict__ h,
                                                     unsigned short* __restrict__ h16) {
    __shared__ float Wlt[H][H + 1];
    __shared__ float Wrt[H][H + 1];
    __shared__ float Al[16][H];
    __shared__ float Hl[16][H];
    int t = threadIdx.x;
    #pragma unroll
    for (int r = 0; r < 16; ++r) {
        int idx = r * 256 + t;
        int f = idx >> 6, k = idx & 63;
        Wlt[k][f] = Wl[idx];
        Wrt[k][f] = Wr[idx];
    }
    int nb = blockIdx.x * 16;
    #pragma unroll
    for (int r = 0; r < 4; ++r) {
        int idx = r * 256 + t;
        ((float*)Al)[idx] = agg[nb * H + idx];
        ((float*)Hl)[idx] = h[nb * H + idx];
    }
    __syncthreads();
    int f = t & 63;
    int q = t >> 6;
    float b = bl[f];
    float acc0 = b, acc1 = b, acc2 = b, acc3 = b;
    #pragma unroll
    for (int k = 0; k < H; ++k) {
        float wl = Wlt[k][f];
        float wr = Wrt[k][f];
        acc0 += Al[q * 4 + 0][k] * wl + Hl[q * 4 + 0][k] * wr;
        acc1 += Al[q * 4 + 1][k] * wl + Hl[q * 4 + 1][k] * wr;
        acc2 += Al[q * 4 + 2][k] * wl + Hl[q * 4 + 2][k] * wr;
        acc3 += Al[q * 4 + 3][k] * wl + Hl[q * 4 + 3][k] * wr;
    }
    float v0 = fmaxf(acc0, 0.f) + Hl[q * 4 + 0][f];
    float v1 = fmaxf(acc1, 0.f) + Hl[q * 4 + 1][f];
    float v2 = fmaxf(acc2, 0.f) + Hl[q * 4 + 2][f];
    float v3 = fmaxf(acc3, 0.f) + Hl[q * 4 + 3][f];
    h[(nb + q * 4 + 0) * H + f] = v0;
    h[(nb + q * 4 + 1) * H + f] = v1;
    h[(nb + q * 4 + 2) * H + f] = v2;
    h[(nb + q * 4 + 3) * H + f] = v3;
    h16[(nb + q * 4 + 0) * H + f] = f2bf(v0);
    h16[(nb + q * 4 + 1) * H + f] = f2bf(v1);
    h16[(nb + q * 4 + 2) * H + f] = f2bf(v2);
    h16[(nb + q * 4 + 3) * H + f] = f2bf(v3);
}

// ---------------------------------------------------------------------------
// Pool + heads (unchanged)
// ---------------------------------------------------------------------------

__global__ __launch_bounds__(256) void pool_kernel(const float* __restrict__ h,
                                                   const int* __restrict__ batch,
                                                   float* __restrict__ gsum,
                                                   float* __restrict__ gcount) {
    int w = blockIdx.x * 4 + (threadIdx.x >> 6);
    int f = threadIdx.x & 63;
    int n0 = w * 256;
    if (n0 >= N_NODES) return;
    int n1 = min(n0 + 256, N_NODES);
    int curg = batch[n0];
    float acc = 0.f;
    int cnt = 0;
    for (int n = n0; n < n1; ++n) {
        int g = batch[n];
        if (g != curg) {
            atomicAdd(&gsum[curg * H + f], acc);
            if (f == 0) atomicAdd(&gcount[curg], (float)cnt);
            acc = 0.f; cnt = 0; curg = g;
        }
        acc += h[n * H + f];
        ++cnt;
    }
    atomicAdd(&gsum[curg * H + f], acc);
    if (f == 0) atomicAdd(&gcount[curg], (float)cnt);
}

__global__ __launch_bounds__(256) void policy_kernel(const float* __restrict__ gsum,
                                                     const float* __restrict__ gcount,
                                                     const float* __restrict__ Wp,
                                                     const float* __restrict__ bp,
                                                     float* __restrict__ out) {
    __shared__ float gr[H];
    int g = blockIdx.y;
    int t = threadIdx.x;
    if (t < H) {
        float inv = 1.0f / fmaxf(gcount[g], 1.0f);
        gr[t] = gsum[g * H + t] * inv;
    }
    __syncthreads();
    int a = blockIdx.x * 256 + t;
    if (a >= A_SZ) return;
    const float4* wp4 = (const float4*)(Wp + a * H);
    float acc = bp[a];
    #pragma unroll
    for (int c = 0; c < 16; ++c) {
        float4 wv = wp4[c];
        acc += gr[4 * c + 0] * wv.x + gr[4 * c + 1] * wv.y
             + gr[4 * c + 2] * wv.z + gr[4 * c + 3] * wv.w;
    }
    out[g * A_SZ + a] = acc;
}

__global__ void value_kernel(const float* __restrict__ gsum, const float* __restrict__ gcount,
                             const float* __restrict__ Wv, const float* __restrict__ bv,
                             float* __restrict__ out) {
    int g = threadIdx.x;
    if (g >= G_SZ) return;
    float inv = 1.0f / fmaxf(gcount[g], 1.0f);
    float acc = bv[0];
    #pragma unroll
    for (int k = 0; k < H; ++k) acc += gsum[g * H + k] * inv * Wv[k];
    out[G_SZ * A_SZ + g] = tanhf(acc);
}

// ---------------------------------------------------------------------------

extern "C" void kernel_launch(void* const* d_in, const int* in_sizes, int n_in,
                              void* d_out, int out_size, void* d_ws, size_t ws_size,
                              hipStream_t stream) {
    const float* x     = (const float*)d_in[0];
    const int*   ei    = (const int*)d_in[1];
    const int*   batch = (const int*)d_in[2];
    const float* W_enc = (const float*)d_in[3];
    const float* b_enc = (const float*)d_in[4];
    const float* Wl    = (const float*)d_in[5];
    const float* bl    = (const float*)d_in[6];
    const float* Wr    = (const float*)d_in[7];
    const float* Wp    = (const float*)d_in[8];
    const float* bp    = (const float*)d_in[9];
    const float* Wv    = (const float*)d_in[10];
    const float* bv    = (const float*)d_in[11];
    float* out = (float*)d_out;

    char* ws = (char*)d_ws;
    size_t off = 0;
    auto alloc = [&](size_t bytes) {
        char* p = ws + off;
        off = (off + bytes + 255) & ~(size_t)255;
        return p;
    };
    float* h            = (float*)alloc((size_t)N_NODES * H * 4);
    float* agg          = (float*)alloc((size_t)N_NODES * H * 4);
    unsigned short* h16 = (unsigned short*)alloc((size_t)N_NODES * H * 2);
    int* row_start      = (int*)alloc((size_t)(N_NODES + 1) * 4);
    float* inv_deg      = (float*)alloc((size_t)N_NODES * 4);
    int* src_sorted     = (int*)alloc((size_t)N_EDGES * 4);
    unsigned int* pairs = (unsigned int*)alloc((size_t)N_EDGES * 4);
    int* bhist          = (int*)alloc((NBUCK + 8) * 4);
    int* bucket_base    = (int*)alloc((NBUCK + 8) * 4);
    int* bcursor        = (int*)alloc((NBUCK + 8) * 4);
    float* gsum         = (float*)alloc((size_t)(G_SZ * H + G_SZ) * 4);
    float* gcount       = gsum + G_SZ * H;

    const int NB = (N_NODES + 255) / 256;  // 391

    // CSR build (bucketed)
    hipMemsetAsync(bhist, 0, NBUCK * 4, stream);
    bucket_hist_kernel<<<NEBLK, 256, 0, stream>>>(ei, bhist);
    bucket_scan_kernel<<<1, 512, 0, stream>>>(bhist, bucket_base, bcursor);
    bucket_scatter_kernel<<<NEBLK, 256, 0, stream>>>(ei, bcursor, pairs);
    bucket_rank_kernel<<<NBUCK, 256, 0, stream>>>(pairs, bucket_base, row_start,
                                                  inv_deg, src_sorted);

    encoder_kernel<<<N_NODES / 4, 256, 0, stream>>>(x, W_enc, b_enc, h, h16);

    for (int l = 0; l < L_LAYERS; ++l) {
        aggregate_kernel<<<N_NODES / 8, 256, 0, stream>>>(h16, row_start, src_sorted,
                                                          inv_deg, agg);
        update_kernel<<<N_NODES / 16, 256, 0, stream>>>(Wl + (size_t)l * H * H, bl + l * H,
                                                        Wr + (size_t)l * H * H, agg, h, h16);
    }

    hipMemsetAsync(gsum, 0, (size_t)(G_SZ * H + G_SZ) * 4, stream);
    pool_kernel<<<(NB + 3) / 4, 256, 0, stream>>>(h, batch, gsum, gcount);
    policy_kernel<<<dim3((A_SZ + 255) / 256, G_SZ), 256, 0, stream>>>(gsum, gcount, Wp, bp, out);
    value_kernel<<<1, 64, 0, stream>>>(gsum, gcount, Wv, bv, out);
}